// Round 9
// baseline (193.172 us; speedup 1.0000x reference)
//
#include <hip/hip_runtime.h>

#define TT 512
#define BB 512
#define NN 64
#define LN2F 0.69314718055994530942f
#define SCH 64           // chunk length; 8 chunks cover t = 1..511
#define EXACT_THRESH 32  // boundary chunks shorter than this are replayed exactly

typedef _Float16 half8_t __attribute__((ext_vector_type(8)));
typedef float    f32x4   __attribute__((ext_vector_type(4)));

union AFrag { int u[4]; half8_t h; };

__device__ __forceinline__ float wave_max(float v) {
    #pragma unroll
    for (int off = 32; off > 0; off >>= 1)
        v = fmaxf(v, __shfl_xor(v, off, 64));
    return v;
}

__device__ __forceinline__ float wave_sum(float v) {
    #pragma unroll
    for (int off = 32; off > 0; off >>= 1)
        v += __shfl_xor(v, off, 64);
    return v;
}

__device__ __forceinline__ int wave_sum_i(int v) {
    #pragma unroll
    for (int off = 32; off > 0; off >>= 1)
        v += __shfl_xor(v, off, 64);
    return v;
}

__device__ __forceinline__ float bcast_lane(float v, int lane) {
    return __uint_as_float(__builtin_amdgcn_readlane(__float_as_uint(v), lane));
}

// Zero the scalar output (harness poisons d_out with 0xAA before every launch).
__global__ void zero_kernel(float* __restrict__ out) {
    if (threadIdx.x == 0 && blockIdx.x == 0) out[0] = 0.0f;
}

// r21 = r18 (rank-1 chunking, all math verified) with each chain in its OWN
// wave (TLP instead of intra-wave interleave):
//   waves 0-7 : F chains, chunk c = wv (wave 0 starts from the true u0)
//   waves 8-14: B chains R_c = M_c^T 1 for chunks 1-7 (transposed B-frags,
//               w applied on input, rows descending) — r18-verbatim math
//   wave 15   : gold score; result passed via LDS (ONE atomic per block)
// Per-step chain is r12's proven 497-cyc matvec (pack -> 8 bpermute -> 8 MFMA
// C-chained -> select -> readfirstlane e-probe -> ldexp). 4 chain-waves/SIMD
// (launch_bounds 1024,4 => VGPR<=128) hide the chain latency via TLP; 512
// blocks run as 2 staggered rounds on 256 CUs. Emit: coalesced 1-dword/lane
// loads, 4-deep register rotation. Combine + boundary replay: r18-verbatim.
__global__ __launch_bounds__(1024, 4) void crf_fwd_kernel(
    const float* __restrict__ emit,
    const float* __restrict__ trans,
    const float* __restrict__ strans,
    const float* __restrict__ etrans,
    const int*   __restrict__ target,
    const void*  __restrict__ maskp,
    float* __restrict__ out)
{
    const int b   = blockIdx.x;
    const int tid = threadIdx.x;
    const int k   = tid & 63;
    const int wv  = tid >> 6;   // 0..7 F, 8..14 B, 15 gold

    __shared__ float FL[8][NN];   // scaled F_c (state-indexed)
    __shared__ float RL[8][NN];   // scaled R_c
    __shared__ int   esF[8], esB[8];
    __shared__ float gsh;         // gold score handoff

    const int*           mi32 = (const int*)maskp;
    const unsigned char* mi8  = (const unsigned char*)maskp;
    // mask[0,:] is all-true (lengths >= 1): byte encoding -> word0 == 0x01010101.
    const bool bytemode = (mi32[0] == 0x01010101);

    // len[b] = sum_t mask[t,b] (monotone mask)
    int cnt = 0;
    #pragma unroll
    for (int i = 0; i < TT / 64; ++i) {
        const size_t tb = (size_t)(i * 64 + k) * BB + b;
        cnt += bytemode ? (mi8[tb] != 0) : (mi32[tb] != 0);
    }
    const int len = wave_sum_i(cnt);   // wave-uniform

    const int  q    = k >> 4;
    const int  nlo  = k & 15;
    const bool bit4 = (k & 16) != 0;
    const bool bit5 = (k & 32) != 0;

    const float* eptr = emit + (size_t)b * NN + k;   // row stride BB*NN

    // bpermute byte-addresses (r12): A frag (kh, reg r) sources lane 32kh+8q+2r.
    int addrs[8];
    #pragma unroll
    for (int kh = 0; kh < 2; ++kh)
        #pragma unroll
        for (int r = 0; r < 4; ++r)
            addrs[4 * kh + r] = 128 * kh + 32 * q + 8 * r;

    const f32x4 zero4 = {0.f, 0.f, 0.f, 0.f};

    const int  Bc    = (len >= 2) ? ((len - 2) / SCH) : 0;   // boundary chunk id
    const int  sB    = len - (1 + SCH * Bc);                 // its step count (0..64)
    const bool exact = (Bc >= 1) && (sB < EXACT_THRESH);

    auto ldr = [&](int t) -> float {
        t = t < 0 ? 0 : (t > TT - 1 ? TT - 1 : t);
        return eptr[(size_t)t * BB * NN];
    };

    half8_t Bf[4][2];     // this wave's matrix fragments (F or B orientation)
    float m0loc = 0.f;
    float uX = 1.f;
    int   eX = 0;

    // r12-verified matvec: pack -> 8 bpermute -> 8 MFMA (K-halves C-chained)
    // -> lane k selects its own output state via 3 cndmasks.
    auto matvec = [&](float x) -> float {
        const float uo = __int_as_float(
            __builtin_amdgcn_mov_dpp(__float_as_int(x), 0xB1, 0xF, 0xF, true));
        const int pkv = __builtin_bit_cast(int, __builtin_amdgcn_cvt_pkrtz(x, uo));
        AFrag a0f, a1f;
        #pragma unroll
        for (int r = 0; r < 4; ++r) {
            a0f.u[r] = __builtin_amdgcn_ds_bpermute(addrs[r],     pkv);
            a1f.u[r] = __builtin_amdgcn_ds_bpermute(addrs[4 + r], pkv);
        }
        const f32x4 aA0 = __builtin_amdgcn_mfma_f32_16x16x32_f16(a0f.h, Bf[0][0], zero4, 0, 0, 0);
        const f32x4 aA1 = __builtin_amdgcn_mfma_f32_16x16x32_f16(a0f.h, Bf[1][0], zero4, 0, 0, 0);
        const f32x4 aA2 = __builtin_amdgcn_mfma_f32_16x16x32_f16(a0f.h, Bf[2][0], zero4, 0, 0, 0);
        const f32x4 aA3 = __builtin_amdgcn_mfma_f32_16x16x32_f16(a0f.h, Bf[3][0], zero4, 0, 0, 0);
        const f32x4 ac0 = __builtin_amdgcn_mfma_f32_16x16x32_f16(a1f.h, Bf[0][1], aA0, 0, 0, 0);
        const f32x4 ac1 = __builtin_amdgcn_mfma_f32_16x16x32_f16(a1f.h, Bf[1][1], aA1, 0, 0, 0);
        const f32x4 ac2 = __builtin_amdgcn_mfma_f32_16x16x32_f16(a1f.h, Bf[2][1], aA2, 0, 0, 0);
        const f32x4 ac3 = __builtin_amdgcn_mfma_f32_16x16x32_f16(a1f.h, Bf[3][1], aA3, 0, 0, 0);
        const float sLo = bit4 ? ac1[0] : ac0[0];
        const float sHi = bit4 ? ac3[0] : ac2[0];
        return bit5 ? sHi : sLo;
    };

    // fwd step: y = matvec(u); e from PRE-w probe (+4 guard); u = ldexp(y*w,-e)
    auto stepF = [&](float w) {
        const float y = matvec(uX);
        const int e = (int)((__builtin_amdgcn_readfirstlane(__float_as_uint(y)) >> 23) & 0xff) - 127 + 4;
        uX = ldexpf(y * w, -e);
        eX += e + 2;   // +2 restores the 0.25=2^-2 folded into B (exact)
    };
    // bwd step (M_t^T = E~ diag(w_t)): v = u*w first, then matvec.
    auto stepB = [&](float w) {
        const float y = matvec(uX * w);
        const int e = (int)((__builtin_amdgcn_readfirstlane(__float_as_uint(y)) >> 23) & 0xff) - 127 + 4;
        uX = ldexpf(y, -e);
        eX += e + 2;
    };

    if (wv < 15) {
        const bool fwd = (wv < 8);
        const int  c   = fwd ? wv : (wv - 7);   // B waves cover chunks 1..7

        // B fragments. fwd (y_n = sum_k x_k exp(trans[k][n])): r12-verbatim.
        // bwd (y_n = sum_k x_k exp(trans[n][k])): transposed load. [r18-verified]
        #pragma unroll
        for (int g = 0; g < 4; ++g) {
            #pragma unroll
            for (int kh = 0; kh < 2; ++kh) {
                AFrag bf;
                #pragma unroll
                for (int jp = 0; jp < 4; ++jp) {
                    const int krow = 32 * kh + 8 * q + 2 * jp;
                    const int ncol = 16 * g + nlo;
                    float e0, e1;
                    if (fwd) {
                        e0 = 0.25f * __expf(trans[(krow + 0) * NN + ncol]);
                        e1 = 0.25f * __expf(trans[(krow + 1) * NN + ncol]);
                    } else {
                        e0 = 0.25f * __expf(trans[ncol * NN + (krow + 0)]);
                        e1 = 0.25f * __expf(trans[ncol * NN + (krow + 1)]);
                    }
                    bf.u[jp] = __builtin_bit_cast(int, __builtin_amdgcn_cvt_pkrtz(e0, e1));
                }
                Bf[g][kh] = bf.h;
            }
        }

        if (fwd && c == 0) {
            const float alpha0 = eptr[0] + strans[k];
            m0loc = bcast_lane(alpha0, 0);
            uX = __expf(alpha0 - m0loc);
        }

        const int t0  = 1 + SCH * c;
        const int nst = min(max(len - t0, 0), SCH);
        const int tL  = t0 + nst - 1;   // bwd iterates descending from tL

        auto rowd = [&](int j) -> float { return ldr(fwd ? (t0 + j) : (tL - j)); };

        // 4-deep register rotation over nst steps
        float r0 = rowd(0), r1 = rowd(1), r2 = rowd(2), r3 = rowd(3);
        int i = 0;
        #pragma unroll 1
        for (; i + 4 <= nst; i += 4) {
            const float w0 = __expf(r0), w1 = __expf(r1);
            const float w2 = __expf(r2), w3 = __expf(r3);
            r0 = rowd(i + 4); r1 = rowd(i + 5); r2 = rowd(i + 6); r3 = rowd(i + 7);
            if (fwd) { stepF(w0); stepF(w1); stepF(w2); stepF(w3); }
            else     { stepB(w0); stepB(w1); stepB(w2); stepB(w3); }
        }
        if (i     < nst) { const float w = __expf(r0); fwd ? stepF(w) : stepB(w); }
        if (i + 1 < nst) { const float w = __expf(r1); fwd ? stepF(w) : stepB(w); }
        if (i + 2 < nst) { const float w = __expf(r2); fwd ? stepF(w) : stepB(w); }

        if (fwd) { FL[c][k] = uX; if (k == 0) esF[c] = eX; }
        else     { RL[c][k] = uX; if (k == 0) esB[c] = eX; }
    } else {
        // ---- wave 15: fused gold score (overlaps the chains) ----
        int tvals[TT / 64];
        #pragma unroll
        for (int i = 0; i < TT / 64; ++i)
            tvals[i] = target[(size_t)(64 * i + k) * BB + b];

        float g = 0.f;
        int prev_last = 0;
        #pragma unroll
        for (int i = 0; i < TT / 64; ++i) {
            const int tt = 64 * i + k;
            const int tgt = tvals[i];
            int tprev = __shfl_up(tvals[i], 1, 64);
            if (k == 0) tprev = prev_last;                       // carry across i
            prev_last = __builtin_amdgcn_readlane(tvals[i], 63);
            if (tt < len) {
                float v = emit[((size_t)tt * BB + b) * NN + tgt];
                v += (tt == 0) ? strans[tgt] : trans[tprev * NN + tgt];
                if (tt == len - 1) v += etrans[tgt];
                g += v;
            }
        }
        g = wave_sum(g);
        if (k == 0) gsh = g;
    }

    __syncthreads();

    // ---- combine + optional exact replay + epilogue: wave 0 (holds F Bf) ----
    if (wv == 0) {
        float x    = FL[0][k];
        float Ltot = LN2F * (float)esF[0];
        const int Cend = exact ? (Bc - 1) : Bc;

        // rank-1: M_c x = F_c (R_c^T x)/(1^T F_c); chunk scales via esB.
        for (int c2 = 1; c2 <= Cend; ++c2) {
            const float num = wave_sum(RL[c2][k] * x);
            const float den = wave_sum(FL[c2][k]);
            Ltot += __logf(num / den) + LN2F * (float)esB[c2];
            x = FL[c2][k];
        }

        if (exact) {
            // replay the short boundary chunk exactly from x (wave 0's Bf is
            // the forward matrix; 4-deep prefetch rotation)
            uX = x; eX = 0;
            const int t0B = 1 + SCH * Bc;
            float p0 = ldr(t0B + 0), p1 = ldr(t0B + 1);
            float p2 = ldr(t0B + 2), p3 = ldr(t0B + 3);
            int j = 0;
            #pragma unroll 1
            for (; j + 4 <= sB; j += 4) {
                const float w0 = __expf(p0), w1 = __expf(p1);
                const float w2 = __expf(p2), w3 = __expf(p3);
                p0 = ldr(t0B + j + 4); p1 = ldr(t0B + j + 5);
                p2 = ldr(t0B + j + 6); p3 = ldr(t0B + j + 7);
                stepF(w0); stepF(w1); stepF(w2); stepF(w3);
            }
            if (j     < sB) stepF(__expf(p0));
            if (j + 1 < sB) stepF(__expf(p1));
            if (j + 2 < sB) stepF(__expf(p2));
            x = uX;
            Ltot += LN2F * (float)eX;
        }

        // logZ_b = m0 + Ltot + logsumexp_k(log(x_k) + etrans[k])
        const float la = __logf(x) + etrans[k];   // x==0 -> -inf -> exp -> 0: fine
        const float m2 = wave_max(la);
        const float sm = wave_sum(__expf(la - m2));
        const float logZ_b = m0loc + Ltot + m2 + __logf(sm);

        if (k == 0) atomicAdd(out, logZ_b - gsh);   // single atomic per block
    }
}

extern "C" void kernel_launch(void* const* d_in, const int* in_sizes, int n_in,
                              void* d_out, int out_size, void* d_ws, size_t ws_size,
                              hipStream_t stream) {
    const float* emit   = (const float*)d_in[0];
    const float* trans  = (const float*)d_in[1];
    const float* strans = (const float*)d_in[2];
    const float* etrans = (const float*)d_in[3];
    const int*   target = (const int*)d_in[4];
    const void*  mask   = d_in[5];
    float* out = (float*)d_out;

    hipLaunchKernelGGL(zero_kernel, dim3(1), dim3(64), 0, stream, out);
    hipLaunchKernelGGL(crf_fwd_kernel, dim3(BB), dim3(1024), 0, stream,
                       emit, trans, strans, etrans, target, mask, out);
}

// Round 10
// 192.889 us; speedup vs baseline: 1.0015x; 1.0015x over previous
//
#include <hip/hip_runtime.h>

#define TT 512
#define BB 512
#define NN 64
#define LN2F 0.69314718055994530942f
#define SCH 64           // chunk length; 8 chunks cover t = 1..511
#define EXACT_THRESH 32  // boundary chunks shorter than this are replayed exactly

typedef _Float16 half8_t __attribute__((ext_vector_type(8)));
typedef float    f32x4   __attribute__((ext_vector_type(4)));

union AFrag { int u[4]; half8_t h; };

__device__ __forceinline__ float wave_max(float v) {
    #pragma unroll
    for (int off = 32; off > 0; off >>= 1)
        v = fmaxf(v, __shfl_xor(v, off, 64));
    return v;
}

__device__ __forceinline__ float wave_sum(float v) {
    #pragma unroll
    for (int off = 32; off > 0; off >>= 1)
        v += __shfl_xor(v, off, 64);
    return v;
}

__device__ __forceinline__ int wave_sum_i(int v) {
    #pragma unroll
    for (int off = 32; off > 0; off >>= 1)
        v += __shfl_xor(v, off, 64);
    return v;
}

__device__ __forceinline__ float bcast_lane(float v, int lane) {
    return __uint_as_float(__builtin_amdgcn_readlane(__float_as_uint(v), lane));
}

// Zero the scalar output (harness poisons d_out with 0xAA before every launch).
__global__ void zero_kernel(float* __restrict__ out) {
    if (threadIdx.x == 0 && blockIdx.x == 0) out[0] = 0.0f;
}

// r22 = r21 with the spill removed: __launch_bounds__(1024) only. r21's
// (1024,4) asked for 4 waves/EU BEYOND the block's own 4 waves/SIMD -> VGPR
// capped at 64 -> Bf/addrs/prefetch spilled to scratch (WRITE_SIZE 32KB ->
// 44MB, ~850 cyc/step). A 1024-thread block needs VGPR<=128 for residency;
// the chain working set (~90 VGPR, cf. r18's 84) fits with zero spills.
// Structure (verified r18 math, r12 step):
//   waves 0-7 : F chains, chunk c = wv (wave 0 from the true u0)
//   waves 8-14: B chains R_c = M_c^T 1 (transposed B-frags, w on input,
//               rows descending)
//   wave 15   : gold score -> LDS handoff, ONE atomic per block
// Per-step: pack -> 8 bpermute -> 8 MFMA C-chained -> select -> e-probe ->
// ldexp (497 cyc chain); 4 chain-waves/SIMD hide it via TLP. Combine:
// rank-1 identity M_c x = F_c (R_c^T x)/(1^T F_c) + exact boundary replay.
__global__ __launch_bounds__(1024) void crf_fwd_kernel(
    const float* __restrict__ emit,
    const float* __restrict__ trans,
    const float* __restrict__ strans,
    const float* __restrict__ etrans,
    const int*   __restrict__ target,
    const void*  __restrict__ maskp,
    float* __restrict__ out)
{
    const int b   = blockIdx.x;
    const int tid = threadIdx.x;
    const int k   = tid & 63;
    const int wv  = tid >> 6;   // 0..7 F, 8..14 B, 15 gold

    __shared__ float FL[8][NN];   // scaled F_c (state-indexed)
    __shared__ float RL[8][NN];   // scaled R_c
    __shared__ int   esF[8], esB[8];
    __shared__ float gsh;         // gold score handoff

    const int*           mi32 = (const int*)maskp;
    const unsigned char* mi8  = (const unsigned char*)maskp;
    // mask[0,:] is all-true (lengths >= 1): byte encoding -> word0 == 0x01010101.
    const bool bytemode = (mi32[0] == 0x01010101);

    // len[b] = sum_t mask[t,b] (monotone mask)
    int cnt = 0;
    #pragma unroll
    for (int i = 0; i < TT / 64; ++i) {
        const size_t tb = (size_t)(i * 64 + k) * BB + b;
        cnt += bytemode ? (mi8[tb] != 0) : (mi32[tb] != 0);
    }
    const int len = wave_sum_i(cnt);   // wave-uniform

    const int  q    = k >> 4;
    const int  nlo  = k & 15;
    const bool bit4 = (k & 16) != 0;
    const bool bit5 = (k & 32) != 0;

    const float* eptr = emit + (size_t)b * NN + k;   // row stride BB*NN

    // bpermute byte-addresses (r12): A frag (kh, reg r) sources lane 32kh+8q+2r.
    int addrs[8];
    #pragma unroll
    for (int kh = 0; kh < 2; ++kh)
        #pragma unroll
        for (int r = 0; r < 4; ++r)
            addrs[4 * kh + r] = 128 * kh + 32 * q + 8 * r;

    const f32x4 zero4 = {0.f, 0.f, 0.f, 0.f};

    const int  Bc    = (len >= 2) ? ((len - 2) / SCH) : 0;   // boundary chunk id
    const int  sB    = len - (1 + SCH * Bc);                 // its step count (0..64)
    const bool exact = (Bc >= 1) && (sB < EXACT_THRESH);

    auto ldr = [&](int t) -> float {
        t = t < 0 ? 0 : (t > TT - 1 ? TT - 1 : t);
        return eptr[(size_t)t * BB * NN];
    };

    half8_t Bf[4][2];     // this wave's matrix fragments (F or B orientation)
    float m0loc = 0.f;
    float uX = 1.f;
    int   eX = 0;

    // r12-verified matvec: pack -> 8 bpermute -> 8 MFMA (K-halves C-chained)
    // -> lane k selects its own output state via 3 cndmasks.
    auto matvec = [&](float x) -> float {
        const float uo = __int_as_float(
            __builtin_amdgcn_mov_dpp(__float_as_int(x), 0xB1, 0xF, 0xF, true));
        const int pkv = __builtin_bit_cast(int, __builtin_amdgcn_cvt_pkrtz(x, uo));
        AFrag a0f, a1f;
        #pragma unroll
        for (int r = 0; r < 4; ++r) {
            a0f.u[r] = __builtin_amdgcn_ds_bpermute(addrs[r],     pkv);
            a1f.u[r] = __builtin_amdgcn_ds_bpermute(addrs[4 + r], pkv);
        }
        const f32x4 aA0 = __builtin_amdgcn_mfma_f32_16x16x32_f16(a0f.h, Bf[0][0], zero4, 0, 0, 0);
        const f32x4 aA1 = __builtin_amdgcn_mfma_f32_16x16x32_f16(a0f.h, Bf[1][0], zero4, 0, 0, 0);
        const f32x4 aA2 = __builtin_amdgcn_mfma_f32_16x16x32_f16(a0f.h, Bf[2][0], zero4, 0, 0, 0);
        const f32x4 aA3 = __builtin_amdgcn_mfma_f32_16x16x32_f16(a0f.h, Bf[3][0], zero4, 0, 0, 0);
        const f32x4 ac0 = __builtin_amdgcn_mfma_f32_16x16x32_f16(a1f.h, Bf[0][1], aA0, 0, 0, 0);
        const f32x4 ac1 = __builtin_amdgcn_mfma_f32_16x16x32_f16(a1f.h, Bf[1][1], aA1, 0, 0, 0);
        const f32x4 ac2 = __builtin_amdgcn_mfma_f32_16x16x32_f16(a1f.h, Bf[2][1], aA2, 0, 0, 0);
        const f32x4 ac3 = __builtin_amdgcn_mfma_f32_16x16x32_f16(a1f.h, Bf[3][1], aA3, 0, 0, 0);
        const float sLo = bit4 ? ac1[0] : ac0[0];
        const float sHi = bit4 ? ac3[0] : ac2[0];
        return bit5 ? sHi : sLo;
    };

    // fwd step: y = matvec(u); e from PRE-w probe (+4 guard); u = ldexp(y*w,-e)
    auto stepF = [&](float w) {
        const float y = matvec(uX);
        const int e = (int)((__builtin_amdgcn_readfirstlane(__float_as_uint(y)) >> 23) & 0xff) - 127 + 4;
        uX = ldexpf(y * w, -e);
        eX += e + 2;   // +2 restores the 0.25=2^-2 folded into B (exact)
    };
    // bwd step (M_t^T = E~ diag(w_t)): v = u*w first, then matvec.
    auto stepB = [&](float w) {
        const float y = matvec(uX * w);
        const int e = (int)((__builtin_amdgcn_readfirstlane(__float_as_uint(y)) >> 23) & 0xff) - 127 + 4;
        uX = ldexpf(y, -e);
        eX += e + 2;
    };

    if (wv < 15) {
        const bool fwd = (wv < 8);
        const int  c   = fwd ? wv : (wv - 7);   // B waves cover chunks 1..7

        // B fragments. fwd (y_n = sum_k x_k exp(trans[k][n])): r12-verbatim.
        // bwd (y_n = sum_k x_k exp(trans[n][k])): transposed load. [r18-verified]
        #pragma unroll
        for (int g = 0; g < 4; ++g) {
            #pragma unroll
            for (int kh = 0; kh < 2; ++kh) {
                AFrag bf;
                #pragma unroll
                for (int jp = 0; jp < 4; ++jp) {
                    const int krow = 32 * kh + 8 * q + 2 * jp;
                    const int ncol = 16 * g + nlo;
                    float e0, e1;
                    if (fwd) {
                        e0 = 0.25f * __expf(trans[(krow + 0) * NN + ncol]);
                        e1 = 0.25f * __expf(trans[(krow + 1) * NN + ncol]);
                    } else {
                        e0 = 0.25f * __expf(trans[ncol * NN + (krow + 0)]);
                        e1 = 0.25f * __expf(trans[ncol * NN + (krow + 1)]);
                    }
                    bf.u[jp] = __builtin_bit_cast(int, __builtin_amdgcn_cvt_pkrtz(e0, e1));
                }
                Bf[g][kh] = bf.h;
            }
        }

        if (fwd && c == 0) {
            const float alpha0 = eptr[0] + strans[k];
            m0loc = bcast_lane(alpha0, 0);
            uX = __expf(alpha0 - m0loc);
        }

        const int t0  = 1 + SCH * c;
        const int nst = min(max(len - t0, 0), SCH);
        const int tL  = t0 + nst - 1;   // bwd iterates descending from tL

        auto rowd = [&](int j) -> float { return ldr(fwd ? (t0 + j) : (tL - j)); };

        // 4-deep register rotation over nst steps
        float r0 = rowd(0), r1 = rowd(1), r2 = rowd(2), r3 = rowd(3);
        int i = 0;
        #pragma unroll 1
        for (; i + 4 <= nst; i += 4) {
            const float w0 = __expf(r0), w1 = __expf(r1);
            const float w2 = __expf(r2), w3 = __expf(r3);
            r0 = rowd(i + 4); r1 = rowd(i + 5); r2 = rowd(i + 6); r3 = rowd(i + 7);
            if (fwd) { stepF(w0); stepF(w1); stepF(w2); stepF(w3); }
            else     { stepB(w0); stepB(w1); stepB(w2); stepB(w3); }
        }
        if (i     < nst) { const float w = __expf(r0); fwd ? stepF(w) : stepB(w); }
        if (i + 1 < nst) { const float w = __expf(r1); fwd ? stepF(w) : stepB(w); }
        if (i + 2 < nst) { const float w = __expf(r2); fwd ? stepF(w) : stepB(w); }

        if (fwd) { FL[c][k] = uX; if (k == 0) esF[c] = eX; }
        else     { RL[c][k] = uX; if (k == 0) esB[c] = eX; }
    } else {
        // ---- wave 15: fused gold score (overlaps the chains) ----
        int tvals[TT / 64];
        #pragma unroll
        for (int i = 0; i < TT / 64; ++i)
            tvals[i] = target[(size_t)(64 * i + k) * BB + b];

        float g = 0.f;
        int prev_last = 0;
        #pragma unroll
        for (int i = 0; i < TT / 64; ++i) {
            const int tt = 64 * i + k;
            const int tgt = tvals[i];
            int tprev = __shfl_up(tvals[i], 1, 64);
            if (k == 0) tprev = prev_last;                       // carry across i
            prev_last = __builtin_amdgcn_readlane(tvals[i], 63);
            if (tt < len) {
                float v = emit[((size_t)tt * BB + b) * NN + tgt];
                v += (tt == 0) ? strans[tgt] : trans[tprev * NN + tgt];
                if (tt == len - 1) v += etrans[tgt];
                g += v;
            }
        }
        g = wave_sum(g);
        if (k == 0) gsh = g;
    }

    __syncthreads();

    // ---- combine + optional exact replay + epilogue: wave 0 (holds F Bf) ----
    if (wv == 0) {
        float x    = FL[0][k];
        float Ltot = LN2F * (float)esF[0];
        const int Cend = exact ? (Bc - 1) : Bc;

        // rank-1: M_c x = F_c (R_c^T x)/(1^T F_c); chunk scales via esB.
        for (int c2 = 1; c2 <= Cend; ++c2) {
            const float num = wave_sum(RL[c2][k] * x);
            const float den = wave_sum(FL[c2][k]);
            Ltot += __logf(num / den) + LN2F * (float)esB[c2];
            x = FL[c2][k];
        }

        if (exact) {
            // replay the short boundary chunk exactly from x (wave 0's Bf is
            // the forward matrix; 4-deep prefetch rotation)
            uX = x; eX = 0;
            const int t0B = 1 + SCH * Bc;
            float p0 = ldr(t0B + 0), p1 = ldr(t0B + 1);
            float p2 = ldr(t0B + 2), p3 = ldr(t0B + 3);
            int j = 0;
            #pragma unroll 1
            for (; j + 4 <= sB; j += 4) {
                const float w0 = __expf(p0), w1 = __expf(p1);
                const float w2 = __expf(p2), w3 = __expf(p3);
                p0 = ldr(t0B + j + 4); p1 = ldr(t0B + j + 5);
                p2 = ldr(t0B + j + 6); p3 = ldr(t0B + j + 7);
                stepF(w0); stepF(w1); stepF(w2); stepF(w3);
            }
            if (j     < sB) stepF(__expf(p0));
            if (j + 1 < sB) stepF(__expf(p1));
            if (j + 2 < sB) stepF(__expf(p2));
            x = uX;
            Ltot += LN2F * (float)eX;
        }

        // logZ_b = m0 + Ltot + logsumexp_k(log(x_k) + etrans[k])
        const float la = __logf(x) + etrans[k];   // x==0 -> -inf -> exp -> 0: fine
        const float m2 = wave_max(la);
        const float sm = wave_sum(__expf(la - m2));
        const float logZ_b = m0loc + Ltot + m2 + __logf(sm);

        if (k == 0) atomicAdd(out, logZ_b - gsh);   // single atomic per block
    }
}

extern "C" void kernel_launch(void* const* d_in, const int* in_sizes, int n_in,
                              void* d_out, int out_size, void* d_ws, size_t ws_size,
                              hipStream_t stream) {
    const float* emit   = (const float*)d_in[0];
    const float* trans  = (const float*)d_in[1];
    const float* strans = (const float*)d_in[2];
    const float* etrans = (const float*)d_in[3];
    const int*   target = (const int*)d_in[4];
    const void*  mask   = d_in[5];
    float* out = (float*)d_out;

    hipLaunchKernelGGL(zero_kernel, dim3(1), dim3(64), 0, stream, out);
    hipLaunchKernelGGL(crf_fwd_kernel, dim3(BB), dim3(1024), 0, stream,
                       emit, trans, strans, etrans, target, mask, out);
}